// Round 14
// baseline (293.009 us; speedup 1.0000x reference)
//
#include <hip/hip_runtime.h>
#include <hip/hip_fp16.h>

#define NN 50000
#define EE 800000
#define STCOPY 2400000   // halves per ST copy (NN*8*6)

typedef __attribute__((ext_vector_type(4))) float f32x4;
typedef __attribute__((ext_vector_type(8))) short bf16x8;

__device__ inline unsigned short f2b(float f) {
    unsigned u = __float_as_uint(f);
    u += 0x7fff + ((u >> 16) & 1);   // RNE
    return (unsigned short)(u >> 16);
}

__device__ __forceinline__ unsigned cvtpk(float a, float b) {
    unsigned r;
    asm("v_cvt_pk_bf16_f32 %0, %1, %2" : "=v"(r) : "v"(a), "v"(b));
    return r;   // lo = bf16(a), hi = bf16(b)
}

__device__ __forceinline__ bf16x8 cvt8(float4 a, float4 b) {
    union { unsigned u[4]; bf16x8 v; } t;
    t.u[0] = cvtpk(a.x, a.y);
    t.u[1] = cvtpk(a.z, a.w);
    t.u[2] = cvtpk(b.x, b.y);
    t.u[3] = cvtpk(b.z, b.w);
    return t.v;
}

// reduce 8 per-lane partials over the 16-lane lr-group; lane lr ends with the
// full sum of value-index h = lr&7 (lanes lr and lr+8 hold duplicates).
__device__ inline float redt8(const float v[8], int lr) {
    const bool b0 = lr & 1, b1 = lr & 2, b2 = lr & 4;
    float u[4];
#pragma unroll
    for (int m = 0; m < 4; ++m) {
        float keep = b0 ? v[2*m+1] : v[2*m];
        float send = b0 ? v[2*m]   : v[2*m+1];
        u[m] = keep + __shfl_xor(send, 1);
    }
    float w[2];
#pragma unroll
    for (int m = 0; m < 2; ++m) {
        float keep = b1 ? u[2*m+1] : u[2*m];
        float send = b1 ? u[2*m]   : u[2*m+1];
        w[m] = keep + __shfl_xor(send, 2);
    }
    float keep = b2 ? w[1] : w[0];
    float send = b2 ? w[0] : w[1];
    float x = keep + __shfl_xor(send, 4);
    x += __shfl_xor(x, 8);
    return x;
}

// ---- convert 4 weight matrices f32 -> bf16 into ws ----
__global__ void convert_w(const float* __restrict__ Wq, const float* __restrict__ Wk,
                          const float* __restrict__ Wv, const float* __restrict__ Wo,
                          unsigned short* __restrict__ out) {
    int g = blockIdx.x * 256 + threadIdx.x;     // 65536 threads
    int which = g >> 14, idx = g & 16383;
    const float* s = (which == 0) ? Wq : (which == 1) ? Wk : (which == 2) ? Wv : Wo;
    out[g] = f2b(s[idx]);
}

__device__ __forceinline__ void load_a(const float* __restrict__ A, int T,
                                       int lr, int lk, float4 (&fb)[8])
{
    const float* ap = A + ((long)T * 16 + lr) * 128 + lk * 8;
#pragma unroll
    for (int s = 0; s < 4; ++s) {
        fb[2*s]   = *(const float4*)(ap + s * 32);
        fb[2*s+1] = *(const float4*)(ap + s * 32 + 4);
    }
}

// ---- fused q+v projection: reads h_node once, A-prefetch pipelined ----
// Qt: transposed layout [n][dh=16][h=8] bf16; Vb: standard [n][128].
__global__ __launch_bounds__(256) void gemm_qv(
    const float* __restrict__ A,
    const unsigned short* __restrict__ Wq,
    const unsigned short* __restrict__ Wv,
    const float* __restrict__ bq, const float* __restrict__ bv,
    unsigned short* __restrict__ Qt, unsigned short* __restrict__ Vb)
{
    __shared__ __align__(16) unsigned short WsQ[128 * 128];
    __shared__ __align__(16) unsigned short WsV[128 * 128];
    const int t = threadIdx.x;
#pragma unroll
    for (int i = 0; i < 8; ++i) {
        int chunk = t + i * 256;
        int row = chunk >> 4, kc = chunk & 15;
        *(uint4*)(WsQ + (row << 7) + ((kc ^ (row & 15)) << 3)) = *(const uint4*)(Wq + (row << 7) + (kc << 3));
        *(uint4*)(WsV + (row << 7) + ((kc ^ (row & 15)) << 3)) = *(const uint4*)(Wv + (row << 7) + (kc << 3));
    }
    const int wave = t >> 6, lane = t & 63, lr = lane & 15, lk = lane >> 4;
    float bqv[8], bvv[8];
#pragma unroll
    for (int j = 0; j < 8; ++j) { bqv[j] = bq[j * 16 + lr]; bvv[j] = bv[j * 16 + lr]; }
    __syncthreads();

    const int NTt = NN / 16;                    // 3125
    const int nw = gridDim.x * 4;
    const int wid = blockIdx.x * 4 + wave;
    const int run = (NTt + nw - 1) / nw;
    const int t0 = wid * run;
    const int t1 = (t0 + run < NTt) ? t0 + run : NTt;
    if (t0 >= t1) return;

    float4 fb[8];
    load_a(A, t0, lr, lk, fb);

    for (int tile = t0; tile < t1; ++tile) {
        bf16x8 af[4];
#pragma unroll
        for (int s = 0; s < 4; ++s) af[s] = cvt8(fb[2*s], fb[2*s+1]);
        const int tn = (tile + 1 < t1) ? tile + 1 : tile;
        load_a(A, tn, lr, lk, fb);              // issue next tile's loads

        f32x4 aq[8], av[8];
#pragma unroll
        for (int j = 0; j < 8; ++j) { aq[j] = (f32x4){0,0,0,0}; av[j] = (f32x4){0,0,0,0}; }
#pragma unroll
        for (int s = 0; s < 4; ++s) {
#pragma unroll
            for (int j = 0; j < 8; ++j) {
                int brow = j * 16 + lr;
                int kc = s * 4 + lk;
                bf16x8 wq = *(const bf16x8*)(WsQ + (brow << 7) + ((kc ^ (brow & 15)) << 3));
                bf16x8 wv = *(const bf16x8*)(WsV + (brow << 7) + ((kc ^ (brow & 15)) << 3));
                aq[j] = __builtin_amdgcn_mfma_f32_16x16x32_bf16(af[s], wq, aq[j], 0, 0, 0);
                av[j] = __builtin_amdgcn_mfma_f32_16x16x32_bf16(af[s], wv, av[j], 0, 0, 0);
            }
        }
        const long n0 = (long)tile * 16 + lk * 4;
#pragma unroll
        for (int j = 0; j < 8; ++j) {
            int col = j * 16 + lr;
#pragma unroll
            for (int r = 0; r < 4; ++r) Vb[(n0 + r) * 128 + col] = f2b(av[j][r] + bvv[j]);
        }
#pragma unroll
        for (int r = 0; r < 4; ++r) {
            unsigned short q8[8];
#pragma unroll
            for (int j = 0; j < 8; ++j) q8[j] = f2b(aq[j][r] + bqv[j]);
            *(uint4*)(Qt + (n0 + r) * 128 + lr * 8) = *(uint4*)q8;
        }
    }
}

// ================= pipelined fused k-projection + edge attention ============
struct Meta { int sn[4]; int dn[4]; float dv[4]; };

__device__ __forceinline__ void load_meta(int T, int lk,
    const int* __restrict__ src, const int* __restrict__ dst,
    const float* __restrict__ dist, Meta& m)
{
    const int er = T * 16 + lk * 4;             // 16B aligned
    int4 s4 = *(const int4*)(src + er);
    int4 d4 = *(const int4*)(dst + er);
    float4 v4 = *(const float4*)(dist + er);
    m.sn[0] = s4.x; m.sn[1] = s4.y; m.sn[2] = s4.z; m.sn[3] = s4.w;
    m.dn[0] = d4.x; m.dn[1] = d4.y; m.dn[2] = d4.z; m.dn[3] = d4.w;
    m.dv[0] = v4.x; m.dv[1] = v4.y; m.dv[2] = v4.z; m.dv[3] = v4.w;
}

__device__ __forceinline__ void load_q(const unsigned short* __restrict__ Qt,
                                       const Meta& m, int lr,
                                       uint4 (&uqs)[4], uint4 (&uqd)[4])
{
#pragma unroll
    for (int r = 0; r < 4; ++r) {
        uqs[r] = *(const uint4*)(Qt + (long)m.sn[r] * 128 + lr * 8);
        uqd[r] = *(const uint4*)(Qt + (long)m.dn[r] * 128 + lr * 8);
    }
}

__device__ __forceinline__ void mfma_tile(const unsigned short* Ws,
    const float4 (&fb)[8], int lr, int lk, f32x4 (&acc)[8])
{
    bf16x8 af[4];
#pragma unroll
    for (int s = 0; s < 4; ++s) af[s] = cvt8(fb[2*s], fb[2*s+1]);
#pragma unroll
    for (int j = 0; j < 8; ++j) acc[j] = (f32x4){0, 0, 0, 0};
#pragma unroll
    for (int s = 0; s < 4; ++s) {
#pragma unroll
        for (int j = 0; j < 8; ++j) {
            int brow = j * 16 + lr;
            int kc = s * 4 + lk;
            bf16x8 b = *(const bf16x8*)(Ws + (brow << 7) + ((kc ^ (brow & 15)) << 3));
            acc[j] = __builtin_amdgcn_mfma_f32_16x16x32_bf16(af[s], b, acc[j], 0, 0, 0);
        }
    }
}

__device__ __forceinline__ void unpack8(uint4 u, float (&q)[8]) {
    q[0] = __uint_as_float(u.x << 16); q[1] = __uint_as_float(u.x & 0xffff0000u);
    q[2] = __uint_as_float(u.y << 16); q[3] = __uint_as_float(u.y & 0xffff0000u);
    q[4] = __uint_as_float(u.z << 16); q[5] = __uint_as_float(u.z & 0xffff0000u);
    q[6] = __uint_as_float(u.w << 16); q[7] = __uint_as_float(u.w & 0xffff0000u);
}

// ST layout: [n*8+h][6] f16 = {S1,S2,S3,T1,T2,T3}; 3 pk-f16 atomics per (e,h),
// into this block's private copy (contention spread / XCD alignment).
__device__ __forceinline__ void dots_atomic(const f32x4 (&acc)[8],
    const uint4 (&uqs)[4], const uint4 (&uqd)[4], const Meta& m,
    const float (&bkv)[8], float lamv, int lr,
    __half* __restrict__ ST)
{
    const int hoff = (lr & 7);
    const bool hiH = (lr >= 8);
#pragma unroll
    for (int r = 0; r < 4; ++r) {
        float at = __expf(lamv * __logf(m.dv[r]));
        float qs[8], qd[8];
        unpack8(uqs[r], qs);
        unpack8(uqd[r], qd);
        float din[8], dou[8], ddg[8];
#pragma unroll
        for (int j = 0; j < 8; ++j) {
            float kv = acc[j][r] + bkv[j];
            din[j] = kv * qs[j];
            dou[j] = kv * qd[j];
            ddg[j] = qs[j] * qd[j];
        }
        float a1r = redt8(din, lr);
        float a2r = redt8(dou, lr);
        float a3r = redt8(ddg, lr);
        float e1 = __expf(a1r * 0.25f);
        float e2 = __expf(a2r * 0.25f);
        float e3 = __expf(a3r * 0.25f);
        __half* base = ST + ((long)m.dn[r] * 8 + hoff) * 6;
        if (!hiH) {
            unsafeAtomicAdd((__half2*)(base),
                __halves2half2(__float2half(e1), __float2half(e2)));
            unsafeAtomicAdd((__half2*)(base + 2),
                __halves2half2(__float2half(e3), __float2half(e1 * at)));
        } else {
            unsafeAtomicAdd((__half2*)(base + 4),
                __halves2half2(__float2half(e2 * at), __float2half(e3 * at)));
        }
    }
}

__global__ __launch_bounds__(256) void edge_fused(
    const float* __restrict__ A,            // h_edge
    const unsigned short* __restrict__ Wk,
    const float* __restrict__ bk,
    const unsigned short* __restrict__ Qt,
    const int* __restrict__ src, const int* __restrict__ dst,
    const float* __restrict__ dist, const float* __restrict__ lam,
    __half* __restrict__ ST)
{
    __shared__ __align__(16) unsigned short Ws[128 * 128];
    const int t = threadIdx.x;
#pragma unroll
    for (int i = 0; i < 8; ++i) {
        int chunk = t + i * 256;
        int row = chunk >> 4, kc = chunk & 15;
        *(uint4*)(Ws + (row << 7) + ((kc ^ (row & 15)) << 3)) =
            *(const uint4*)(Wk + (row << 7) + (kc << 3));
    }
    const int wave = t >> 6, lane = t & 63, lr = lane & 15, lk = lane >> 4;
    float bkv[8];
#pragma unroll
    for (int j = 0; j < 8; ++j) bkv[j] = bk[j * 16 + lr];
    const float lamv = lam[0];
    __syncthreads();

    // per-block ST copy: blockIdx&7 matches the default round-robin block->XCD
    __half* STl = ST + (size_t)(blockIdx.x & 7) * STCOPY;

    const int NT = EE / 16;
    const int nw = gridDim.x * 4;
    const int wid = blockIdx.x * 4 + wave;
    const int run = (NT + nw - 1) / nw;
    const int t0 = wid * run;
    const int t1 = (t0 + run < NT) ? t0 + run : NT;
    if (t0 >= t1) return;

    Meta mA, mB;
    float4 fb[8];
    uint4 uqsA[4], uqdA[4], uqsB[4], uqdB[4];

    // prologue: tile t0 in flight
    load_meta(t0, lk, src, dst, dist, mA);
    load_a(A, t0, lr, lk, fb);
    load_q(Qt, mA, lr, uqsA, uqdA);

    for (int tt = t0; tt < t1; tt += 2) {
        const int tp = (tt + 1 < t1) ? tt + 1 : t1 - 1;
        const int tq = (tt + 2 < t1) ? tt + 2 : t1 - 1;
        const bool do2 = (tt + 1 < t1);
        // ---- body 1: process tt (A sets), prefetch tp (B sets) ----
        load_meta(tp, lk, src, dst, dist, mB);
        f32x4 acc[8];
        mfma_tile(Ws, fb, lr, lk, acc);     // consumes fb = A(tt)
        load_a(A, tp, lr, lk, fb);          // issue A(tp)
        load_q(Qt, mB, lr, uqsB, uqdB);     // issue Q(tp)
        dots_atomic(acc, uqsA, uqdA, mA, bkv, lamv, lr, STl);
        // ---- body 2: process tp (B sets), prefetch tq (A sets) ----
        load_meta(tq, lk, src, dst, dist, mA);
        f32x4 acc2[8];
        mfma_tile(Ws, fb, lr, lk, acc2);    // consumes fb = A(tp)
        load_a(A, tq, lr, lk, fb);          // issue A(tq)
        load_q(Qt, mA, lr, uqsA, uqdA);     // issue Q(tq)
        if (do2)
            dots_atomic(acc2, uqsB, uqdB, mB, bkv, lamv, lr, STl);
    }
}

// ---- output GEMM: out[N,128] f32 = mish( (Vb * SS(ΣST)) @ Wo^T + bo ) ----
__global__ __launch_bounds__(256) void gemm_out_k(
    const unsigned short* __restrict__ Vb,
    const __half* __restrict__ ST,
    const unsigned short* __restrict__ W,
    const float* __restrict__ bias,
    float* __restrict__ Out)
{
    __shared__ __align__(16) unsigned short As[128 * 128];
    __shared__ __align__(16) unsigned short Ws[128 * 128];
    const int t = threadIdx.x;
    const long mbase = (long)blockIdx.x * 128;

#pragma unroll
    for (int i = 0; i < 8; ++i) {
        int chunk = t + i * 256;
        int row = chunk >> 4, kc = chunk & 15;
        uint4 w = *(const uint4*)(W + (row << 7) + (kc << 3));
        *(uint4*)(Ws + (row << 7) + ((kc ^ (row & 15)) << 3)) = w;
    }
#pragma unroll
    for (int i = 0; i < 8; ++i) {
        int chunk = t + i * 256;
        int row = chunk >> 4, kc = chunk & 15;
        long m = mbase + row;
        unsigned short tmp[8];
        if (m < NN) {
            const long sidx = ((long)m * 8 + (kc >> 1)) * 6;
            float S1 = 0.f, S2 = 0.f, S3 = 0.f, T1 = 0.f, T2 = 0.f, T3 = 0.f;
#pragma unroll
            for (int c = 0; c < 8; ++c) {
                const __half* p = ST + (size_t)c * STCOPY + sidx;
                S1 += __half2float(p[0]); S2 += __half2float(p[1]);
                S3 += __half2float(p[2]); T1 += __half2float(p[3]);
                T2 += __half2float(p[4]); T3 += __half2float(p[5]);
            }
            float ss = T1 / (S1 + 1e-12f) + T2 / (S2 + 1e-12f) + T3 / (S3 + 1e-12f);
            uint4 u = *(const uint4*)(Vb + m * 128 + (kc << 3));
            unsigned arr[4] = {u.x, u.y, u.z, u.w};
#pragma unroll
            for (int jj = 0; jj < 4; ++jj) {
                float lo = __uint_as_float(arr[jj] << 16) * ss;
                float hi = __uint_as_float(arr[jj] & 0xffff0000u) * ss;
                tmp[2 * jj] = f2b(lo);
                tmp[2 * jj + 1] = f2b(hi);
            }
        } else {
#pragma unroll
            for (int j = 0; j < 8; ++j) tmp[j] = 0;
        }
        *(uint4*)(As + (row << 7) + ((kc ^ (row & 15)) << 3)) = *(uint4*)tmp;
    }
    __syncthreads();

    const int wave = t >> 6, lane = t & 63;
    const int lr = lane & 15, lk = lane >> 4;
    f32x4 acc[2][8];
#pragma unroll
    for (int i = 0; i < 2; ++i)
#pragma unroll
        for (int j = 0; j < 8; ++j) acc[i][j] = (f32x4){0.f, 0.f, 0.f, 0.f};

#pragma unroll
    for (int s = 0; s < 4; ++s) {
        bf16x8 a[2];
#pragma unroll
        for (int i = 0; i < 2; ++i) {
            int row = wave * 32 + i * 16 + lr;
            int kc = s * 4 + lk;
            a[i] = *(const bf16x8*)(As + (row << 7) + ((kc ^ (row & 15)) << 3));
        }
#pragma unroll
        for (int j = 0; j < 8; ++j) {
            int row = j * 16 + lr;
            int kc = s * 4 + lk;
            bf16x8 b = *(const bf16x8*)(Ws + (row << 7) + ((kc ^ (row & 15)) << 3));
            acc[0][j] = __builtin_amdgcn_mfma_f32_16x16x32_bf16(a[0], b, acc[0][j], 0, 0, 0);
            acc[1][j] = __builtin_amdgcn_mfma_f32_16x16x32_bf16(a[1], b, acc[1][j], 0, 0, 0);
        }
    }
#pragma unroll
    for (int i = 0; i < 2; ++i)
#pragma unroll
        for (int j = 0; j < 8; ++j) {
            int col = j * 16 + lr;
            float bv_ = bias[col];
#pragma unroll
            for (int r = 0; r < 4; ++r) {
                long m = mbase + wave * 32 + i * 16 + lk * 4 + r;
                if (m < NN) {
                    float x = acc[i][j][r] + bv_;
                    float sp = (x > 15.f) ? x : log1pf(expf(x));
                    Out[m * 128 + col] = x * tanhf(sp);
                }
            }
        }
}

extern "C" void kernel_launch(void* const* d_in, const int* in_sizes, int n_in,
                              void* d_out, int out_size, void* d_ws, size_t ws_size,
                              hipStream_t stream)
{
    const float* h_node = (const float*)d_in[0];
    const float* h_edge = (const float*)d_in[1];
    const float* dist   = (const float*)d_in[2];
    const float* Wq = (const float*)d_in[3];
    const float* bq = (const float*)d_in[4];
    const float* Wk = (const float*)d_in[5];
    const float* bk = (const float*)d_in[6];
    const float* Wv = (const float*)d_in[7];
    const float* bv = (const float*)d_in[8];
    const float* Wo = (const float*)d_in[9];
    const float* bo = (const float*)d_in[10];
    const float* lam = (const float*)d_in[11];
    const int* src = (const int*)d_in[12];
    const int* dst = (const int*)d_in[13];
    float* out = (float*)d_out;

    char* ws = (char*)d_ws;
    unsigned short* Wb = (unsigned short*)ws;                 // 128 KB
    unsigned short* Qt = Wb + 65536;                          // 12.8 MB
    unsigned short* Vb = Qt + (size_t)NN * 128;               // 12.8 MB
    __half* ST = (__half*)(Vb + (size_t)NN * 128);            // 8 x 4.8 MB f16

    hipMemsetAsync(ST, 0, (size_t)8 * STCOPY * sizeof(__half), stream);
    convert_w<<<256, 256, 0, stream>>>(Wq, Wk, Wv, Wo, Wb);

    // q+v projections (h_node read once, A-prefetch pipelined)
    gemm_qv<<<196, 256, 0, stream>>>(h_node, Wb, Wb + 2 * 16384, bq, bv, Qt, Vb);

    // pipelined fused k-projection + attention sums (pk-f16 atomics, 8-way split)
    edge_fused<<<512, 256, 0, stream>>>(h_edge, Wb + 16384, bk, Qt, src, dst, dist, lam, ST);

    // output projection + mish (SS summed over 8 ST copies)
    gemm_out_k<<<391, 256, 0, stream>>>(Vb, ST, Wb + 3 * 16384, bo, out);
}

// Round 15
// 279.971 us; speedup vs baseline: 1.0466x; 1.0466x over previous
//
#include <hip/hip_runtime.h>
#include <hip/hip_fp16.h>

#define NN 50000
#define EE 800000

typedef __attribute__((ext_vector_type(4))) float f32x4;
typedef __attribute__((ext_vector_type(8))) short bf16x8;

__device__ inline unsigned short f2b(float f) {
    unsigned u = __float_as_uint(f);
    u += 0x7fff + ((u >> 16) & 1);   // RNE
    return (unsigned short)(u >> 16);
}

__device__ __forceinline__ unsigned cvtpk(float a, float b) {
    unsigned r;
    asm("v_cvt_pk_bf16_f32 %0, %1, %2" : "=v"(r) : "v"(a), "v"(b));
    return r;   // lo = bf16(a), hi = bf16(b)
}

__device__ __forceinline__ bf16x8 cvt8(float4 a, float4 b) {
    union { unsigned u[4]; bf16x8 v; } t;
    t.u[0] = cvtpk(a.x, a.y);
    t.u[1] = cvtpk(a.z, a.w);
    t.u[2] = cvtpk(b.x, b.y);
    t.u[3] = cvtpk(b.z, b.w);
    return t.v;
}

// reduce 8 per-lane partials over the 16-lane lr-group; lane lr ends with the
// full sum of value-index h = lr&7 (lanes lr and lr+8 hold duplicates).
__device__ inline float redt8(const float v[8], int lr) {
    const bool b0 = lr & 1, b1 = lr & 2, b2 = lr & 4;
    float u[4];
#pragma unroll
    for (int m = 0; m < 4; ++m) {
        float keep = b0 ? v[2*m+1] : v[2*m];
        float send = b0 ? v[2*m]   : v[2*m+1];
        u[m] = keep + __shfl_xor(send, 1);
    }
    float w[2];
#pragma unroll
    for (int m = 0; m < 2; ++m) {
        float keep = b1 ? u[2*m+1] : u[2*m];
        float send = b1 ? u[2*m]   : u[2*m+1];
        w[m] = keep + __shfl_xor(send, 2);
    }
    float keep = b2 ? w[1] : w[0];
    float send = b2 ? w[0] : w[1];
    float x = keep + __shfl_xor(send, 4);
    x += __shfl_xor(x, 8);
    return x;
}

// ---- convert 4 weight matrices f32 -> bf16 into ws ----
__global__ void convert_w(const float* __restrict__ Wq, const float* __restrict__ Wk,
                          const float* __restrict__ Wv, const float* __restrict__ Wo,
                          unsigned short* __restrict__ out) {
    int g = blockIdx.x * 256 + threadIdx.x;     // 65536 threads
    int which = g >> 14, idx = g & 16383;
    const float* s = (which == 0) ? Wq : (which == 1) ? Wk : (which == 2) ? Wv : Wo;
    out[g] = f2b(s[idx]);
}

__device__ __forceinline__ void load_a(const float* __restrict__ A, int T,
                                       int lr, int lk, float4 (&fb)[8])
{
    const float* ap = A + ((long)T * 16 + lr) * 128 + lk * 8;
#pragma unroll
    for (int s = 0; s < 4; ++s) {
        fb[2*s]   = *(const float4*)(ap + s * 32);
        fb[2*s+1] = *(const float4*)(ap + s * 32 + 4);
    }
}

// ---- fused q+v projection: reads h_node once, A-prefetch pipelined ----
// Qt: transposed layout [n][dh=16][h=8] bf16; Vb: standard [n][128].
__global__ __launch_bounds__(256) void gemm_qv(
    const float* __restrict__ A,
    const unsigned short* __restrict__ Wq,
    const unsigned short* __restrict__ Wv,
    const float* __restrict__ bq, const float* __restrict__ bv,
    unsigned short* __restrict__ Qt, unsigned short* __restrict__ Vb)
{
    __shared__ __align__(16) unsigned short WsQ[128 * 128];
    __shared__ __align__(16) unsigned short WsV[128 * 128];
    const int t = threadIdx.x;
#pragma unroll
    for (int i = 0; i < 8; ++i) {
        int chunk = t + i * 256;
        int row = chunk >> 4, kc = chunk & 15;
        *(uint4*)(WsQ + (row << 7) + ((kc ^ (row & 15)) << 3)) = *(const uint4*)(Wq + (row << 7) + (kc << 3));
        *(uint4*)(WsV + (row << 7) + ((kc ^ (row & 15)) << 3)) = *(const uint4*)(Wv + (row << 7) + (kc << 3));
    }
    const int wave = t >> 6, lane = t & 63, lr = lane & 15, lk = lane >> 4;
    float bqv[8], bvv[8];
#pragma unroll
    for (int j = 0; j < 8; ++j) { bqv[j] = bq[j * 16 + lr]; bvv[j] = bv[j * 16 + lr]; }
    __syncthreads();

    const int NTt = NN / 16;                    // 3125
    const int nw = gridDim.x * 4;
    const int wid = blockIdx.x * 4 + wave;
    const int run = (NTt + nw - 1) / nw;
    const int t0 = wid * run;
    const int t1 = (t0 + run < NTt) ? t0 + run : NTt;
    if (t0 >= t1) return;

    float4 fb[8];
    load_a(A, t0, lr, lk, fb);

    for (int tile = t0; tile < t1; ++tile) {
        bf16x8 af[4];
#pragma unroll
        for (int s = 0; s < 4; ++s) af[s] = cvt8(fb[2*s], fb[2*s+1]);
        const int tn = (tile + 1 < t1) ? tile + 1 : tile;
        load_a(A, tn, lr, lk, fb);              // issue next tile's loads

        f32x4 aq[8], av[8];
#pragma unroll
        for (int j = 0; j < 8; ++j) { aq[j] = (f32x4){0,0,0,0}; av[j] = (f32x4){0,0,0,0}; }
#pragma unroll
        for (int s = 0; s < 4; ++s) {
#pragma unroll
            for (int j = 0; j < 8; ++j) {
                int brow = j * 16 + lr;
                int kc = s * 4 + lk;
                bf16x8 wq = *(const bf16x8*)(WsQ + (brow << 7) + ((kc ^ (brow & 15)) << 3));
                bf16x8 wv = *(const bf16x8*)(WsV + (brow << 7) + ((kc ^ (brow & 15)) << 3));
                aq[j] = __builtin_amdgcn_mfma_f32_16x16x32_bf16(af[s], wq, aq[j], 0, 0, 0);
                av[j] = __builtin_amdgcn_mfma_f32_16x16x32_bf16(af[s], wv, av[j], 0, 0, 0);
            }
        }
        const long n0 = (long)tile * 16 + lk * 4;
#pragma unroll
        for (int j = 0; j < 8; ++j) {
            int col = j * 16 + lr;
#pragma unroll
            for (int r = 0; r < 4; ++r) Vb[(n0 + r) * 128 + col] = f2b(av[j][r] + bvv[j]);
        }
#pragma unroll
        for (int r = 0; r < 4; ++r) {
            unsigned short q8[8];
#pragma unroll
            for (int j = 0; j < 8; ++j) q8[j] = f2b(aq[j][r] + bqv[j]);
            *(uint4*)(Qt + (n0 + r) * 128 + lr * 8) = *(uint4*)q8;
        }
    }
}

// ================= pipelined fused k-projection + edge attention ============
struct Meta { int sn[4]; int dn[4]; float dv[4]; };

__device__ __forceinline__ void load_meta(int T, int lk,
    const int* __restrict__ src, const int* __restrict__ dst,
    const float* __restrict__ dist, Meta& m)
{
    const int er = T * 16 + lk * 4;             // 16B aligned
    int4 s4 = *(const int4*)(src + er);
    int4 d4 = *(const int4*)(dst + er);
    float4 v4 = *(const float4*)(dist + er);
    m.sn[0] = s4.x; m.sn[1] = s4.y; m.sn[2] = s4.z; m.sn[3] = s4.w;
    m.dn[0] = d4.x; m.dn[1] = d4.y; m.dn[2] = d4.z; m.dn[3] = d4.w;
    m.dv[0] = v4.x; m.dv[1] = v4.y; m.dv[2] = v4.z; m.dv[3] = v4.w;
}

__device__ __forceinline__ void load_q(const unsigned short* __restrict__ Qt,
                                       const Meta& m, int lr,
                                       uint4 (&uqs)[4], uint4 (&uqd)[4])
{
#pragma unroll
    for (int r = 0; r < 4; ++r) {
        uqs[r] = *(const uint4*)(Qt + (long)m.sn[r] * 128 + lr * 8);
        uqd[r] = *(const uint4*)(Qt + (long)m.dn[r] * 128 + lr * 8);
    }
}

__device__ __forceinline__ void mfma_tile(const unsigned short* Ws,
    const float4 (&fb)[8], int lr, int lk, f32x4 (&acc)[8])
{
    bf16x8 af[4];
#pragma unroll
    for (int s = 0; s < 4; ++s) af[s] = cvt8(fb[2*s], fb[2*s+1]);
#pragma unroll
    for (int j = 0; j < 8; ++j) acc[j] = (f32x4){0, 0, 0, 0};
#pragma unroll
    for (int s = 0; s < 4; ++s) {
#pragma unroll
        for (int j = 0; j < 8; ++j) {
            int brow = j * 16 + lr;
            int kc = s * 4 + lk;
            bf16x8 b = *(const bf16x8*)(Ws + (brow << 7) + ((kc ^ (brow & 15)) << 3));
            acc[j] = __builtin_amdgcn_mfma_f32_16x16x32_bf16(af[s], b, acc[j], 0, 0, 0);
        }
    }
}

__device__ __forceinline__ void unpack8(uint4 u, float (&q)[8]) {
    q[0] = __uint_as_float(u.x << 16); q[1] = __uint_as_float(u.x & 0xffff0000u);
    q[2] = __uint_as_float(u.y << 16); q[3] = __uint_as_float(u.y & 0xffff0000u);
    q[4] = __uint_as_float(u.z << 16); q[5] = __uint_as_float(u.z & 0xffff0000u);
    q[6] = __uint_as_float(u.w << 16); q[7] = __uint_as_float(u.w & 0xffff0000u);
}

// ST layout: [n*8+h][6] f16 = {S1,S2,S3,T1,T2,T3}; 3 pk-f16 atomics per (e,h).
__device__ __forceinline__ void dots_atomic(const f32x4 (&acc)[8],
    const uint4 (&uqs)[4], const uint4 (&uqd)[4], const Meta& m,
    const float (&bkv)[8], float lamv, int lr,
    __half* __restrict__ ST)
{
    const int hoff = (lr & 7);
    const bool hiH = (lr >= 8);
#pragma unroll
    for (int r = 0; r < 4; ++r) {
        float at = __expf(lamv * __logf(m.dv[r]));
        float qs[8], qd[8];
        unpack8(uqs[r], qs);
        unpack8(uqd[r], qd);
        float din[8], dou[8], ddg[8];
#pragma unroll
        for (int j = 0; j < 8; ++j) {
            float kv = acc[j][r] + bkv[j];
            din[j] = kv * qs[j];
            dou[j] = kv * qd[j];
            ddg[j] = qs[j] * qd[j];
        }
        float a1r = redt8(din, lr);
        float a2r = redt8(dou, lr);
        float a3r = redt8(ddg, lr);
        float e1 = __expf(a1r * 0.25f);
        float e2 = __expf(a2r * 0.25f);
        float e3 = __expf(a3r * 0.25f);
        __half* base = ST + ((long)m.dn[r] * 8 + hoff) * 6;
        if (!hiH) {
            unsafeAtomicAdd((__half2*)(base),
                __halves2half2(__float2half(e1), __float2half(e2)));
            unsafeAtomicAdd((__half2*)(base + 2),
                __halves2half2(__float2half(e3), __float2half(e1 * at)));
        } else {
            unsafeAtomicAdd((__half2*)(base + 4),
                __halves2half2(__float2half(e2 * at), __float2half(e3 * at)));
        }
    }
}

__global__ __launch_bounds__(256) void edge_fused(
    const float* __restrict__ A,            // h_edge
    const unsigned short* __restrict__ Wk,
    const float* __restrict__ bk,
    const unsigned short* __restrict__ Qt,
    const int* __restrict__ src, const int* __restrict__ dst,
    const float* __restrict__ dist, const float* __restrict__ lam,
    __half* __restrict__ ST)
{
    __shared__ __align__(16) unsigned short Ws[128 * 128];
    const int t = threadIdx.x;
#pragma unroll
    for (int i = 0; i < 8; ++i) {
        int chunk = t + i * 256;
        int row = chunk >> 4, kc = chunk & 15;
        *(uint4*)(Ws + (row << 7) + ((kc ^ (row & 15)) << 3)) =
            *(const uint4*)(Wk + (row << 7) + (kc << 3));
    }
    const int wave = t >> 6, lane = t & 63, lr = lane & 15, lk = lane >> 4;
    float bkv[8];
#pragma unroll
    for (int j = 0; j < 8; ++j) bkv[j] = bk[j * 16 + lr];
    const float lamv = lam[0];
    __syncthreads();

    const int NT = EE / 16;
    const int nw = gridDim.x * 4;
    const int wid = blockIdx.x * 4 + wave;
    const int run = (NT + nw - 1) / nw;
    const int t0 = wid * run;
    const int t1 = (t0 + run < NT) ? t0 + run : NT;
    if (t0 >= t1) return;

    Meta mA, mB;
    float4 fb[8];
    uint4 uqsA[4], uqdA[4], uqsB[4], uqdB[4];

    // prologue: tile t0 in flight
    load_meta(t0, lk, src, dst, dist, mA);
    load_a(A, t0, lr, lk, fb);
    load_q(Qt, mA, lr, uqsA, uqdA);

    for (int tt = t0; tt < t1; tt += 2) {
        const int tp = (tt + 1 < t1) ? tt + 1 : t1 - 1;
        const int tq = (tt + 2 < t1) ? tt + 2 : t1 - 1;
        const bool do2 = (tt + 1 < t1);
        // ---- body 1: process tt (A sets), prefetch tp (B sets) ----
        load_meta(tp, lk, src, dst, dist, mB);
        f32x4 acc[8];
        mfma_tile(Ws, fb, lr, lk, acc);     // consumes fb = A(tt)
        load_a(A, tp, lr, lk, fb);          // issue A(tp)
        load_q(Qt, mB, lr, uqsB, uqdB);     // issue Q(tp)
        dots_atomic(acc, uqsA, uqdA, mA, bkv, lamv, lr, ST);
        // ---- body 2: process tp (B sets), prefetch tq (A sets) ----
        load_meta(tq, lk, src, dst, dist, mA);
        f32x4 acc2[8];
        mfma_tile(Ws, fb, lr, lk, acc2);    // consumes fb = A(tp)
        load_a(A, tq, lr, lk, fb);          // issue A(tq)
        load_q(Qt, mA, lr, uqsA, uqdA);     // issue Q(tq)
        if (do2)
            dots_atomic(acc2, uqsB, uqdB, mB, bkv, lamv, lr, ST);
    }
}

// ---- output GEMM: out[N,128] f32 = mish( (Vb * SS(ST)) @ Wo^T + bo ) ----
__global__ __launch_bounds__(256) void gemm_out_k(
    const unsigned short* __restrict__ Vb,
    const __half* __restrict__ ST,
    const unsigned short* __restrict__ W,
    const float* __restrict__ bias,
    float* __restrict__ Out)
{
    __shared__ __align__(16) unsigned short As[128 * 128];
    __shared__ __align__(16) unsigned short Ws[128 * 128];
    const int t = threadIdx.x;
    const long mbase = (long)blockIdx.x * 128;

#pragma unroll
    for (int i = 0; i < 8; ++i) {
        int chunk = t + i * 256;
        int row = chunk >> 4, kc = chunk & 15;
        uint4 w = *(const uint4*)(W + (row << 7) + (kc << 3));
        *(uint4*)(Ws + (row << 7) + ((kc ^ (row & 15)) << 3)) = w;
    }
#pragma unroll
    for (int i = 0; i < 8; ++i) {
        int chunk = t + i * 256;
        int row = chunk >> 4, kc = chunk & 15;
        long m = mbase + row;
        unsigned short tmp[8];
        if (m < NN) {
            const __half* p = ST + ((long)m * 8 + (kc >> 1)) * 6;
            float S1 = __half2float(p[0]), S2 = __half2float(p[1]);
            float S3 = __half2float(p[2]), T1 = __half2float(p[3]);
            float T2 = __half2float(p[4]), T3 = __half2float(p[5]);
            float ss = T1 / (S1 + 1e-12f) + T2 / (S2 + 1e-12f) + T3 / (S3 + 1e-12f);
            uint4 u = *(const uint4*)(Vb + m * 128 + (kc << 3));
            unsigned arr[4] = {u.x, u.y, u.z, u.w};
#pragma unroll
            for (int jj = 0; jj < 4; ++jj) {
                float lo = __uint_as_float(arr[jj] << 16) * ss;
                float hi = __uint_as_float(arr[jj] & 0xffff0000u) * ss;
                tmp[2 * jj] = f2b(lo);
                tmp[2 * jj + 1] = f2b(hi);
            }
        } else {
#pragma unroll
            for (int j = 0; j < 8; ++j) tmp[j] = 0;
        }
        *(uint4*)(As + (row << 7) + ((kc ^ (row & 15)) << 3)) = *(uint4*)tmp;
    }
    __syncthreads();

    const int wave = t >> 6, lane = t & 63;
    const int lr = lane & 15, lk = lane >> 4;
    f32x4 acc[2][8];
#pragma unroll
    for (int i = 0; i < 2; ++i)
#pragma unroll
        for (int j = 0; j < 8; ++j) acc[i][j] = (f32x4){0.f, 0.f, 0.f, 0.f};

#pragma unroll
    for (int s = 0; s < 4; ++s) {
        bf16x8 a[2];
#pragma unroll
        for (int i = 0; i < 2; ++i) {
            int row = wave * 32 + i * 16 + lr;
            int kc = s * 4 + lk;
            a[i] = *(const bf16x8*)(As + (row << 7) + ((kc ^ (row & 15)) << 3));
        }
#pragma unroll
        for (int j = 0; j < 8; ++j) {
            int row = j * 16 + lr;
            int kc = s * 4 + lk;
            bf16x8 b = *(const bf16x8*)(Ws + (row << 7) + ((kc ^ (row & 15)) << 3));
            acc[0][j] = __builtin_amdgcn_mfma_f32_16x16x32_bf16(a[0], b, acc[0][j], 0, 0, 0);
            acc[1][j] = __builtin_amdgcn_mfma_f32_16x16x32_bf16(a[1], b, acc[1][j], 0, 0, 0);
        }
    }
#pragma unroll
    for (int i = 0; i < 2; ++i)
#pragma unroll
        for (int j = 0; j < 8; ++j) {
            int col = j * 16 + lr;
            float bv_ = bias[col];
#pragma unroll
            for (int r = 0; r < 4; ++r) {
                long m = mbase + wave * 32 + i * 16 + lk * 4 + r;
                if (m < NN) {
                    float x = acc[i][j][r] + bv_;
                    float sp = (x > 15.f) ? x : log1pf(expf(x));
                    Out[m * 128 + col] = x * tanhf(sp);
                }
            }
        }
}

extern "C" void kernel_launch(void* const* d_in, const int* in_sizes, int n_in,
                              void* d_out, int out_size, void* d_ws, size_t ws_size,
                              hipStream_t stream)
{
    const float* h_node = (const float*)d_in[0];
    const float* h_edge = (const float*)d_in[1];
    const float* dist   = (const float*)d_in[2];
    const float* Wq = (const float*)d_in[3];
    const float* bq = (const float*)d_in[4];
    const float* Wk = (const float*)d_in[5];
    const float* bk = (const float*)d_in[6];
    const float* Wv = (const float*)d_in[7];
    const float* bv = (const float*)d_in[8];
    const float* Wo = (const float*)d_in[9];
    const float* bo = (const float*)d_in[10];
    const float* lam = (const float*)d_in[11];
    const int* src = (const int*)d_in[12];
    const int* dst = (const int*)d_in[13];
    float* out = (float*)d_out;

    char* ws = (char*)d_ws;
    unsigned short* Wb = (unsigned short*)ws;                 // 128 KB
    unsigned short* Qt = Wb + 65536;                          // 12.8 MB
    unsigned short* Vb = Qt + (size_t)NN * 128;               // 12.8 MB
    __half* ST = (__half*)(Vb + (size_t)NN * 128);            // 4.8 MB f16

    hipMemsetAsync(ST, 0, (size_t)NN * 8 * 6 * sizeof(__half), stream);
    convert_w<<<256, 256, 0, stream>>>(Wq, Wk, Wv, Wo, Wb);

    // q+v projections (h_node read once, A-prefetch pipelined)
    gemm_qv<<<196, 256, 0, stream>>>(h_node, Wb, Wb + 2 * 16384, bq, bv, Qt, Vb);

    // pipelined fused k-projection + attention segment sums (pk-f16 atomics)
    edge_fused<<<512, 256, 0, stream>>>(h_edge, Wb + 16384, bk, Qt, src, dst, dist, lam, ST);

    // output projection + mish (SS computed inline from ST)
    gemm_out_k<<<391, 256, 0, stream>>>(Vb, ST, Wb + 3 * 16384, bo, out);
}